// Round 2
// baseline (371.655 us; speedup 1.0000x reference)
//
#include <hip/hip_runtime.h>
#include <hip/hip_bf16.h>

#define DIM 256
#define HID 64
#define HW 4096          // 64*64
#define KK 2304          // DIM*9
#define LW 72            // LDS row stride (floats): 64 interior + halo + align pad

// ---------------- Kernel A: pool + (last block per batch) weight generation ----------------
__global__ __launch_bounds__(256) void pool_gen_kernel(const float* __restrict__ x,
                                                       const float* __restrict__ w1,
                                                       const float* __restrict__ gamma,
                                                       const float* __restrict__ beta,
                                                       const float* __restrict__ mean,
                                                       const float* __restrict__ var,
                                                       const float* __restrict__ w2,
                                                       const float* __restrict__ b2,
                                                       float* __restrict__ pooled,
                                                       float* __restrict__ dyn,
                                                       unsigned int* __restrict__ cnt) {
    int plane = blockIdx.x;                       // b*DIM + c, 8192 planes
    int b = plane >> 8;
    int tid = threadIdx.x;

    // ---- phase 1: mean over this plane ----
    const float4* p = (const float4*)(x + (size_t)plane * HW);
    float s = 0.f;
#pragma unroll
    for (int k = 0; k < 4; ++k) {
        float4 v = p[tid + k * 256];
        s += (v.x + v.y) + (v.z + v.w);
    }
#pragma unroll
    for (int off = 32; off > 0; off >>= 1) s += __shfl_down(s, off, 64);

    __shared__ float ws4[4];
    __shared__ unsigned int lastflag;
    int wid = tid >> 6, lane = tid & 63;
    if (lane == 0) ws4[wid] = s;
    __syncthreads();
    if (tid == 0) {
        float t = (ws4[0] + ws4[1]) + (ws4[2] + ws4[3]);
        pooled[plane] = t * (1.0f / (float)HW);
        __threadfence();                               // release pooled[plane]
        unsigned int old = atomicAdd(&cnt[b], 1u);     // device-scope
        lastflag = (old == 255u) ? 1u : 0u;
    }
    __syncthreads();
    if (!lastflag) return;

    // ---- phase 2: this block is the last finisher for batch b -> generate dyn[b] ----
    __threadfence();                                   // acquire all pooled writes
    __shared__ float sp[DIM];
    __shared__ float sig[HID];
    sp[tid] = pooled[b * DIM + tid];
    __syncthreads();
    if (tid < HID) {
        const float4* wr = (const float4*)(w1 + tid * DIM);
        const float4* s4 = (const float4*)sp;
        float acc = 0.f;
#pragma unroll
        for (int i = 0; i < DIM / 4; ++i) {
            float4 v = wr[i]; float4 u = s4[i];
            acc += v.x * u.x + v.y * u.y + v.z * u.z + v.w * u.w;
        }
        float yb = (acc - mean[tid]) * rsqrtf(var[tid] + 1e-5f) * gamma[tid] + beta[tid];
        sig[tid] = 1.0f / (1.0f + expf(-yb));
    }
    __syncthreads();
    // each thread owns 9 consecutive k values (256*9 == 2304)
    const float4* sg4 = (const float4*)sig;
#pragma unroll
    for (int j = 0; j < 9; ++j) {
        int k = tid * 9 + j;
        const float4* wk = (const float4*)(w2 + k * HID);
        float acc = b2[k];
#pragma unroll
        for (int i = 0; i < HID / 4; ++i) {
            float4 v = wk[i]; float4 u = sg4[i];
            acc += v.x * u.x + v.y * u.y + v.z * u.z + v.w * u.w;
        }
        dyn[b * KK + k] = acc;
    }
    // reset counter for cleanliness (memset also re-zeros each call)
    if (tid == 0) cnt[b] = 0u;
}

// ---------------- Kernel B: per-sample depthwise 3x3 conv, one block per (b,c) plane ----------------
__global__ __launch_bounds__(256) void conv_kernel(const float* __restrict__ x,
                                                   const float* __restrict__ dyn,
                                                   const float* __restrict__ bias,
                                                   float* __restrict__ out) {
    int plane = blockIdx.x;                  // b*DIM + c
    int c = plane & (DIM - 1);
    int b = plane >> 8;
    int tid = threadIdx.x;
    const float* xp = x + (size_t)plane * HW;
    float* op = out + (size_t)plane * HW;

    __shared__ float lds[66 * LW];

    // stage plane into LDS first (longest latency), halo + weights interleaved
    const float4* xp4 = (const float4*)xp;
    float4 st[4];
#pragma unroll
    for (int k = 0; k < 4; ++k) st[k] = xp4[tid + k * 256];

    // 3x3 weights for this plane (uniform across block)
    const float* wp = dyn + b * KK + c * 9;
    float w[9];
#pragma unroll
    for (int i = 0; i < 9; ++i) w[i] = wp[i];
    float bv = bias[c];

    // zero the halo: full rows 0 and 65, plus cols 3 and 68 for rows 1..64
    for (int i = tid; i < 272; i += 256) {
        int addr;
        if (i < 72)        addr = i;                         // top row
        else if (i < 144)  addr = 65 * LW + (i - 72);        // bottom row
        else if (i < 208)  addr = (i - 144 + 1) * LW + 3;    // left halo col
        else               addr = (i - 208 + 1) * LW + 68;   // right halo col
        lds[addr] = 0.f;
    }

    // interior: x[gy][gx] -> lds[(gy+1)*LW + 4 + gx]
#pragma unroll
    for (int k = 0; k < 4; ++k) {
        int idx = tid + k * 256;             // 0..1023 float4s
        int row = idx >> 4;                  // 16 float4 per row
        int col4 = idx & 15;
        *(float4*)&lds[(row + 1) * LW + 4 + col4 * 4] = st[k];   // 16B-aligned
    }
    __syncthreads();

    float4* op4 = (float4*)op;
#pragma unroll
    for (int g = 0; g < 4; ++g) {
        int q = tid + g * 256;               // float4 output index
        int row = q >> 4;
        int col0 = (q & 15) * 4;
        float s0 = bv, s1 = bv, s2 = bv, s3 = bv;
#pragma unroll
        for (int dy = 0; dy < 3; ++dy) {
            const float* r = &lds[(row + dy) * LW + 3 + col0];   // r[0] = (row+dy-1, col0-1)
            float a0 = r[0], a1 = r[1], a2 = r[2], a3 = r[3], a4 = r[4], a5 = r[5];
            float w0 = w[dy * 3 + 0], w1v = w[dy * 3 + 1], w2v = w[dy * 3 + 2];
            s0 += w0 * a0 + w1v * a1 + w2v * a2;
            s1 += w0 * a1 + w1v * a2 + w2v * a3;
            s2 += w0 * a2 + w1v * a3 + w2v * a4;
            s3 += w0 * a3 + w1v * a4 + w2v * a5;
        }
        float4 o;
        o.x = s0; o.y = s1; o.z = s2; o.w = s3;
        op4[q] = o;
    }
}

extern "C" void kernel_launch(void* const* d_in, const int* in_sizes, int n_in,
                              void* d_out, int out_size, void* d_ws, size_t ws_size,
                              hipStream_t stream) {
    const float* x     = (const float*)d_in[0];
    const float* w1    = (const float*)d_in[1];
    const float* gamma = (const float*)d_in[2];
    const float* beta  = (const float*)d_in[3];
    const float* mean  = (const float*)d_in[4];
    const float* var   = (const float*)d_in[5];
    const float* w2    = (const float*)d_in[6];
    const float* b2    = (const float*)d_in[7];
    const float* bias  = (const float*)d_in[8];
    float* out = (float*)d_out;

    float* pooled = (float*)d_ws;                 // 8192 floats
    float* dyn = pooled + 8192;                   // 32*2304 = 73728 floats
    unsigned int* cnt = (unsigned int*)(dyn + KK * 32);  // 32 uints

    hipMemsetAsync(cnt, 0, 32 * sizeof(unsigned int), stream);
    pool_gen_kernel<<<8192, 256, 0, stream>>>(x, w1, gamma, beta, mean, var, w2, b2,
                                              pooled, dyn, cnt);
    conv_kernel<<<8192, 256, 0, stream>>>(x, dyn, bias, out);
}

// Round 3
// 77.267 us; speedup vs baseline: 4.8100x; 4.8100x over previous
//
#include <hip/hip_runtime.h>
#include <hip/hip_bf16.h>

#define DIM 256
#define HID 64
#define HW 4096          // 64*64
#define KK 2304          // DIM*9
#define LW 73            // LDS row stride (floats): ODD -> rows cover all mod-4 bank residues

// ---------------- Kernel 1: global average pool over each (b,c) plane ----------------
__global__ __launch_bounds__(256) void pool_kernel(const float* __restrict__ x,
                                                   float* __restrict__ pooled) {
    int plane = blockIdx.x;                       // b*DIM + c, 8192 planes
    const float4* p = (const float4*)(x + (size_t)plane * HW);
    int tid = threadIdx.x;
    float s = 0.f;
#pragma unroll
    for (int k = 0; k < 4; ++k) {
        float4 v = p[tid + k * 256];
        s += (v.x + v.y) + (v.z + v.w);
    }
#pragma unroll
    for (int off = 32; off > 0; off >>= 1) s += __shfl_down(s, off, 64);
    __shared__ float ws[4];
    int wid = tid >> 6, lane = tid & 63;
    if (lane == 0) ws[wid] = s;
    __syncthreads();
    if (tid == 0) {
        float t = (ws[0] + ws[1]) + (ws[2] + ws[3]);
        pooled[plane] = t * (1.0f / (float)HW);
    }
}

// ---------------- Kernel 2: weight gen, 288 blocks = 32 batches x 9 k-chunks ----------------
__global__ __launch_bounds__(256) void gen_kernel(const float* __restrict__ pooled,
                                                  const float* __restrict__ w1,
                                                  const float* __restrict__ gamma,
                                                  const float* __restrict__ beta,
                                                  const float* __restrict__ mean,
                                                  const float* __restrict__ var,
                                                  const float* __restrict__ w2,
                                                  const float* __restrict__ b2,
                                                  float* __restrict__ dyn) {
    int b = blockIdx.x / 9;
    int j = blockIdx.x % 9;
    int tid = threadIdx.x;
    __shared__ float sp[DIM];
    __shared__ float sig[HID];
    sp[tid] = pooled[b * DIM + tid];
    __syncthreads();
    if (tid < HID) {
        const float4* wr = (const float4*)(w1 + tid * DIM);
        const float4* s4 = (const float4*)sp;
        float acc = 0.f;
#pragma unroll
        for (int i = 0; i < DIM / 4; ++i) {
            float4 v = wr[i]; float4 u = s4[i];
            acc += v.x * u.x + v.y * u.y + v.z * u.z + v.w * u.w;
        }
        float yb = (acc - mean[tid]) * rsqrtf(var[tid] + 1e-5f) * gamma[tid] + beta[tid];
        sig[tid] = 1.0f / (1.0f + expf(-yb));
    }
    __syncthreads();
    int k = j * 256 + tid;                        // 9*256 == 2304 == KK
    const float4* wk = (const float4*)(w2 + (size_t)k * HID);
    const float4* sg4 = (const float4*)sig;
    float acc = b2[k];
#pragma unroll
    for (int i = 0; i < HID / 4; ++i) {
        float4 v = wk[i]; float4 u = sg4[i];
        acc += v.x * u.x + v.y * u.y + v.z * u.z + v.w * u.w;
    }
    dyn[b * KK + k] = acc;
}

// ---------------- Kernel 3: per-sample depthwise 3x3 conv, one block per (b,c) plane ----------------
__global__ __launch_bounds__(256) void conv_kernel(const float* __restrict__ x,
                                                   const float* __restrict__ dyn,
                                                   const float* __restrict__ bias,
                                                   float* __restrict__ out) {
    int plane = blockIdx.x;                  // b*DIM + c
    int c = plane & (DIM - 1);
    int b = plane >> 8;
    int tid = threadIdx.x;
    const float* xp = x + (size_t)plane * HW;
    float* op = out + (size_t)plane * HW;

    __shared__ float lds[66 * LW];

    // issue global loads first (longest latency)
    const float4* xp4 = (const float4*)xp;
    float4 st[4];
#pragma unroll
    for (int k = 0; k < 4; ++k) st[k] = xp4[tid + k * 256];

    // 3x3 weights for this plane (uniform across block)
    const float* wp = dyn + b * KK + c * 9;
    float w[9];
#pragma unroll
    for (int i = 0; i < 9; ++i) w[i] = wp[i];
    float bv = bias[c];

    // zero the halo: full rows 0 and 65 (73 each), cols 3 and 68 for rows 1..64
    for (int i = tid; i < 274; i += 256) {
        int addr;
        if (i < 73)        addr = i;                         // top row
        else if (i < 146)  addr = 65 * LW + (i - 73);        // bottom row
        else if (i < 210)  addr = (i - 146 + 1) * LW + 3;    // left halo col
        else               addr = (i - 210 + 1) * LW + 68;   // right halo col
        lds[addr] = 0.f;
    }

    // interior: x[gy][gx] -> lds[(gy+1)*LW + 4 + gx]; scalar writes (LW=73 unaligned for b128)
#pragma unroll
    for (int k = 0; k < 4; ++k) {
        int idx = tid + k * 256;             // 0..1023 float4s
        int row = idx >> 4;                  // 16 float4 per row
        int col4 = idx & 15;
        float* dst = &lds[(row + 1) * LW + 4 + col4 * 4];
        dst[0] = st[k].x; dst[1] = st[k].y; dst[2] = st[k].z; dst[3] = st[k].w;
    }
    __syncthreads();

    float4* op4 = (float4*)op;
#pragma unroll
    for (int g = 0; g < 4; ++g) {
        int q = tid + g * 256;               // float4 output index
        int row = q >> 4;
        int col0 = (q & 15) * 4;
        float s0 = bv, s1 = bv, s2 = bv, s3 = bv;
#pragma unroll
        for (int dy = 0; dy < 3; ++dy) {
            const float* r = &lds[(row + dy) * LW + 3 + col0];   // r[0] = (row+dy-1, col0-1)
            float a0 = r[0], a1 = r[1], a2 = r[2], a3 = r[3], a4 = r[4], a5 = r[5];
            float w0 = w[dy * 3 + 0], w1v = w[dy * 3 + 1], w2v = w[dy * 3 + 2];
            s0 += w0 * a0 + w1v * a1 + w2v * a2;
            s1 += w0 * a1 + w1v * a2 + w2v * a3;
            s2 += w0 * a2 + w1v * a3 + w2v * a4;
            s3 += w0 * a3 + w1v * a4 + w2v * a5;
        }
        float4 o;
        o.x = s0; o.y = s1; o.z = s2; o.w = s3;
        op4[q] = o;
    }
}

extern "C" void kernel_launch(void* const* d_in, const int* in_sizes, int n_in,
                              void* d_out, int out_size, void* d_ws, size_t ws_size,
                              hipStream_t stream) {
    const float* x     = (const float*)d_in[0];
    const float* w1    = (const float*)d_in[1];
    const float* gamma = (const float*)d_in[2];
    const float* beta  = (const float*)d_in[3];
    const float* mean  = (const float*)d_in[4];
    const float* var   = (const float*)d_in[5];
    const float* w2    = (const float*)d_in[6];
    const float* b2    = (const float*)d_in[7];
    const float* bias  = (const float*)d_in[8];
    float* out = (float*)d_out;

    float* pooled = (float*)d_ws;            // 8192 floats
    float* dyn = pooled + 8192;              // 32*2304 = 73728 floats

    pool_kernel<<<8192, 256, 0, stream>>>(x, pooled);
    gen_kernel<<<288, 256, 0, stream>>>(pooled, w1, gamma, beta, mean, var, w2, b2, dyn);
    conv_kernel<<<8192, 256, 0, stream>>>(x, dyn, bias, out);
}

// Round 4
// 70.059 us; speedup vs baseline: 5.3049x; 1.1029x over previous
//
#include <hip/hip_runtime.h>
#include <hip/hip_bf16.h>

#define DIM 256
#define HID 64
#define HW 4096          // 64*64
#define KK 2304          // DIM*9
#define LW 72            // LDS row stride (floats); per-row skew provides bank spread

// skew(R) = ((R>>2) + G[R&3]) & 3 with G = {0,0,2,3}.
// Chosen so that BOTH stride-4 row quadruples (compute reads: R=4u+d, u lane-varying)
// and stride-1 row quadruples (staging writes: R=R0+rr, R0===1 mod 4) hit 4 distinct
// mod-4 bank residue classes -> 32 banks, 2-way, conflict-free.
__device__ __forceinline__ int skew_of(int R) {
    int r3 = R & 3;
    int g = (r3 & 2) ? r3 : 0;       // {0,0,2,3}
    return ((R >> 2) + g) & 3;
}

// ---------------- Kernel 1: global average pool over each (b,c) plane ----------------
__global__ __launch_bounds__(256) void pool_kernel(const float* __restrict__ x,
                                                   float* __restrict__ pooled) {
    int plane = blockIdx.x;                       // b*DIM + c, 8192 planes
    const float4* p = (const float4*)(x + (size_t)plane * HW);
    int tid = threadIdx.x;
    float s = 0.f;
#pragma unroll
    for (int k = 0; k < 4; ++k) {
        float4 v = p[tid + k * 256];
        s += (v.x + v.y) + (v.z + v.w);
    }
#pragma unroll
    for (int off = 32; off > 0; off >>= 1) s += __shfl_down(s, off, 64);
    __shared__ float ws[4];
    int wid = tid >> 6, lane = tid & 63;
    if (lane == 0) ws[wid] = s;
    __syncthreads();
    if (tid == 0) {
        float t = (ws[0] + ws[1]) + (ws[2] + ws[3]);
        pooled[plane] = t * (1.0f / (float)HW);
    }
}

// ---------------- Kernel 2: sigmoid(BN(pooled @ w1^T)) -> sig[32][64] ----------------
__global__ __launch_bounds__(64) void sig_kernel(const float* __restrict__ pooled,
                                                 const float* __restrict__ w1,
                                                 const float* __restrict__ gamma,
                                                 const float* __restrict__ beta,
                                                 const float* __restrict__ mean,
                                                 const float* __restrict__ var,
                                                 float* __restrict__ sigg) {
    int b = blockIdx.x;              // 32 blocks
    int t = threadIdx.x;             // 64 threads
    __shared__ float sp[DIM];
    ((float4*)sp)[t] = ((const float4*)(pooled + b * DIM))[t];
    __syncthreads();
    const float4* wr = (const float4*)(w1 + t * DIM);
    const float4* s4 = (const float4*)sp;
    float acc = 0.f;
#pragma unroll
    for (int i = 0; i < DIM / 4; ++i) {
        float4 v = wr[i]; float4 u = s4[i];
        acc += v.x * u.x + v.y * u.y + v.z * u.z + v.w * u.w;
    }
    float yb = (acc - mean[t]) * rsqrtf(var[t] + 1e-5f) * gamma[t] + beta[t];
    sigg[b * HID + t] = 1.0f / (1.0f + expf(-yb));
}

// ---------------- Kernel 3: depthwise 3x3 conv, 4x4 outputs/thread, in-block dyn-gen ----------------
__global__ __launch_bounds__(256) void conv_kernel(const float* __restrict__ x,
                                                   const float* __restrict__ sigg,
                                                   const float* __restrict__ w2,
                                                   const float* __restrict__ b2,
                                                   const float* __restrict__ bias,
                                                   float* __restrict__ out) {
    int plane = blockIdx.x;                  // b*DIM + c
    int c = plane & (DIM - 1);
    int b = plane >> 8;
    int tid = threadIdx.x;
    const float* xp = x + (size_t)plane * HW;

    __shared__ float lds[66 * LW];
    __shared__ float wsh[12];

    // 1) issue x global loads first (longest latency)
    const float4* xp4 = (const float4*)xp;
    float4 st[4];
#pragma unroll
    for (int k = 0; k < 4; ++k) st[k] = xp4[tid + k * 256];

    // 2) threads 0..8 generate this plane's 9 dyn weights from sig (L2-resident w2 slice)
    if (tid < 9) {
        int kk = c * 9 + tid;
        const float4* wk = (const float4*)(w2 + (size_t)kk * HID);
        const float4* sg = (const float4*)(sigg + b * HID);
        float acc = b2[kk];
#pragma unroll
        for (int i = 0; i < HID / 4; ++i) {
            float4 v = wk[i]; float4 u = sg[i];
            acc += v.x * u.x + v.y * u.y + v.z * u.z + v.w * u.w;
        }
        wsh[tid] = acc;
    }

    // 3) zero halo cells DISJOINT from staged interior (no extra barrier needed):
    //    rows 0 and 65 fully; per row R=1..64 only cols skew+3 (left) and skew+68 (right).
    for (int i = tid; i < 272; i += 256) {
        int addr;
        if (i < 72)        addr = i;                          // top halo row
        else if (i < 144)  addr = 65 * LW + (i - 72);         // bottom halo row
        else {
            int z = i - 144;                                  // 0..127
            int R = 1 + (z >> 1);
            addr = R * LW + skew_of(R) + 3 + (z & 1) * 65;    // left / right halo cell
        }
        lds[addr] = 0.f;
    }

    // 4) stage interior: x[row][col] -> lds[(row+1)*LW + skew + 4 + col] (scalar, skewed)
#pragma unroll
    for (int k = 0; k < 4; ++k) {
        int idx = tid + k * 256;                 // float4 index over plane
        int R = (idx >> 4) + 1;
        int col0 = (idx & 15) * 4;
        float* dst = &lds[R * LW + skew_of(R) + 4 + col0];
        dst[0] = st[k].x; dst[1] = st[k].y; dst[2] = st[k].z; dst[3] = st[k].w;
    }
    __syncthreads();

    // 5) weights + bias to regs
    float w[9];
#pragma unroll
    for (int i = 0; i < 9; ++i) w[i] = wsh[i];
    float bv = bias[c];

    // 6) 4x4 tile per thread: rows 4u..4u+3, cols 4j..4j+3; read 6x6 patch with vertical reuse
    int u = tid >> 4, j = tid & 15;
    float acc[4][4];
#pragma unroll
    for (int m = 0; m < 4; ++m)
#pragma unroll
        for (int i = 0; i < 4; ++i) acc[m][i] = bv;

#define CONTRIB(m, t)                                                          \
    {                                                                          \
        float w0 = w[(t)*3 + 0], w1v = w[(t)*3 + 1], w2v = w[(t)*3 + 2];       \
        acc[m][0] += w0 * a0 + w1v * a1 + w2v * a2;                            \
        acc[m][1] += w0 * a1 + w1v * a2 + w2v * a3;                            \
        acc[m][2] += w0 * a2 + w1v * a3 + w2v * a4;                            \
        acc[m][3] += w0 * a3 + w1v * a4 + w2v * a5;                            \
    }
#define READROW(d)                                                             \
    float a0, a1, a2, a3, a4, a5;                                              \
    {                                                                          \
        int R = 4 * u + (d);                                                   \
        const float* r = &lds[R * LW + skew_of(R) + 3 + 4 * j];                \
        a0 = r[0]; a1 = r[1]; a2 = r[2]; a3 = r[3]; a4 = r[4]; a5 = r[5];      \
    }

    { READROW(0) CONTRIB(0, 0) }
    { READROW(1) CONTRIB(0, 1) CONTRIB(1, 0) }
    { READROW(2) CONTRIB(0, 2) CONTRIB(1, 1) CONTRIB(2, 0) }
    { READROW(3) CONTRIB(1, 2) CONTRIB(2, 1) CONTRIB(3, 0) }
    { READROW(4) CONTRIB(2, 2) CONTRIB(3, 1) }
    { READROW(5) CONTRIB(3, 2) }
#undef READROW
#undef CONTRIB

    // 7) store: 4 float4 rows
    float4* op4 = (float4*)(out + (size_t)plane * HW);
#pragma unroll
    for (int m = 0; m < 4; ++m) {
        float4 o;
        o.x = acc[m][0]; o.y = acc[m][1]; o.z = acc[m][2]; o.w = acc[m][3];
        op4[(4 * u + m) * 16 + j] = o;
    }
}

extern "C" void kernel_launch(void* const* d_in, const int* in_sizes, int n_in,
                              void* d_out, int out_size, void* d_ws, size_t ws_size,
                              hipStream_t stream) {
    const float* x     = (const float*)d_in[0];
    const float* w1    = (const float*)d_in[1];
    const float* gamma = (const float*)d_in[2];
    const float* beta  = (const float*)d_in[3];
    const float* mean  = (const float*)d_in[4];
    const float* var   = (const float*)d_in[5];
    const float* w2    = (const float*)d_in[6];
    const float* b2    = (const float*)d_in[7];
    const float* bias  = (const float*)d_in[8];
    float* out = (float*)d_out;

    float* pooled = (float*)d_ws;            // 8192 floats
    float* sigg = pooled + 8192;             // 32*64 floats

    pool_kernel<<<8192, 256, 0, stream>>>(x, pooled);
    sig_kernel<<<32, 64, 0, stream>>>(pooled, w1, gamma, beta, mean, var, sigg);
    conv_kernel<<<8192, 256, 0, stream>>>(x, sigg, w2, b2, bias, out);
}

// Round 6
// 69.378 us; speedup vs baseline: 5.3570x; 1.0098x over previous
//
#include <hip/hip_runtime.h>
#include <hip/hip_bf16.h>

#define DIM 256
#define HID 64
#define HW 4096          // 64*64
#define KK 2304          // DIM*9
#define LW 72            // LDS row stride (floats); per-row skew provides bank spread

typedef float f4 __attribute__((ext_vector_type(4)));   // native vector for nontemporal builtins

// skew(R) = ((R>>2) + G[R&3]) & 3 with G = {0,0,2,3}.
// Chosen so that BOTH stride-4 row quadruples (compute reads: R=4u+d, u lane-varying)
// and stride-1 row quadruples (staging writes) hit 4 distinct mod-4 bank residue
// classes -> 32 banks, 2-way, conflict-free.
__device__ __forceinline__ int skew_of(int R) {
    int r3 = R & 3;
    int g = (r3 & 2) ? r3 : 0;       // {0,0,2,3}
    return ((R >> 2) + g) & 3;
}

// ---------------- Kernel 1: global average pool over each (b,c) plane ----------------
__global__ __launch_bounds__(256) void pool_kernel(const float* __restrict__ x,
                                                   float* __restrict__ pooled) {
    int plane = blockIdx.x;                       // b*DIM + c, 8192 planes
    const float4* p = (const float4*)(x + (size_t)plane * HW);
    int tid = threadIdx.x;
    float s = 0.f;
#pragma unroll
    for (int k = 0; k < 4; ++k) {
        float4 v = p[tid + k * 256];              // normal load: allocate x in L2/L3
        s += (v.x + v.y) + (v.z + v.w);
    }
#pragma unroll
    for (int off = 32; off > 0; off >>= 1) s += __shfl_down(s, off, 64);
    __shared__ float ws[4];
    int wid = tid >> 6, lane = tid & 63;
    if (lane == 0) ws[wid] = s;
    __syncthreads();
    if (tid == 0) {
        float t = (ws[0] + ws[1]) + (ws[2] + ws[3]);
        pooled[plane] = t * (1.0f / (float)HW);
    }
}

// ---------------- Kernel 2: sigmoid(BN(pooled @ w1^T)) -> sig[32][64] ----------------
__global__ __launch_bounds__(64) void sig_kernel(const float* __restrict__ pooled,
                                                 const float* __restrict__ w1,
                                                 const float* __restrict__ gamma,
                                                 const float* __restrict__ beta,
                                                 const float* __restrict__ mean,
                                                 const float* __restrict__ var,
                                                 float* __restrict__ sigg) {
    int b = blockIdx.x;              // 32 blocks
    int t = threadIdx.x;             // 64 threads
    __shared__ float sp[DIM];
    ((float4*)sp)[t] = ((const float4*)(pooled + b * DIM))[t];
    __syncthreads();
    const float4* wr = (const float4*)(w1 + t * DIM);
    const float4* s4 = (const float4*)sp;
    float acc = 0.f;
#pragma unroll
    for (int i = 0; i < DIM / 4; ++i) {
        float4 v = wr[i]; float4 u = s4[i];
        acc += v.x * u.x + v.y * u.y + v.z * u.z + v.w * u.w;
    }
    float yb = (acc - mean[t]) * rsqrtf(var[t] + 1e-5f) * gamma[t] + beta[t];
    sigg[b * HID + t] = 1.0f / (1.0f + expf(-yb));
}

// ---------------- Kernel 3: depthwise 3x3 conv, 4x4 outputs/thread, in-block dyn-gen ----------------
// x loads are non-temporal (last use; x is L3-resident from pool). out stores are
// non-temporal (streaming, never re-read) so they don't evict x from L3.
__global__ __launch_bounds__(256) void conv_kernel(const float* __restrict__ x,
                                                   const float* __restrict__ sigg,
                                                   const float* __restrict__ w2,
                                                   const float* __restrict__ b2,
                                                   const float* __restrict__ bias,
                                                   float* __restrict__ out) {
    int plane = blockIdx.x;                  // b*DIM + c
    int c = plane & (DIM - 1);
    int b = plane >> 8;
    int tid = threadIdx.x;
    const float* xp = x + (size_t)plane * HW;

    __shared__ float lds[66 * LW];
    __shared__ float wsh[12];

    // 1) issue x global loads first (longest latency); non-temporal (single use)
    const f4* xp4 = (const f4*)xp;
    f4 st[4];
#pragma unroll
    for (int k = 0; k < 4; ++k) st[k] = __builtin_nontemporal_load(&xp4[tid + k * 256]);

    // 2) threads 0..8 generate this plane's 9 dyn weights from sig (L2-resident w2 slice)
    if (tid < 9) {
        int kk = c * 9 + tid;
        const float4* wk = (const float4*)(w2 + (size_t)kk * HID);
        const float4* sg = (const float4*)(sigg + b * HID);
        float acc = b2[kk];
#pragma unroll
        for (int i = 0; i < HID / 4; ++i) {
            float4 v = wk[i]; float4 u = sg[i];
            acc += v.x * u.x + v.y * u.y + v.z * u.z + v.w * u.w;
        }
        wsh[tid] = acc;
    }

    // 3) zero halo cells DISJOINT from staged interior (no extra barrier needed):
    //    rows 0 and 65 fully; per row R=1..64 only cols skew+3 (left) and skew+68 (right).
    for (int i = tid; i < 272; i += 256) {
        int addr;
        if (i < 72)        addr = i;                          // top halo row
        else if (i < 144)  addr = 65 * LW + (i - 72);         // bottom halo row
        else {
            int z = i - 144;                                  // 0..127
            int R = 1 + (z >> 1);
            addr = R * LW + skew_of(R) + 3 + (z & 1) * 65;    // left / right halo cell
        }
        lds[addr] = 0.f;
    }

    // 4) stage interior: x[row][col] -> lds[(row+1)*LW + skew + 4 + col] (scalar, skewed)
#pragma unroll
    for (int k = 0; k < 4; ++k) {
        int idx = tid + k * 256;                 // float4 index over plane
        int R = (idx >> 4) + 1;
        int col0 = (idx & 15) * 4;
        float* dst = &lds[R * LW + skew_of(R) + 4 + col0];
        dst[0] = st[k].x; dst[1] = st[k].y; dst[2] = st[k].z; dst[3] = st[k].w;
    }
    __syncthreads();

    // 5) weights + bias to regs
    float w[9];
#pragma unroll
    for (int i = 0; i < 9; ++i) w[i] = wsh[i];
    float bv = bias[c];

    // 6) 4x4 tile per thread: rows 4u..4u+3, cols 4j..4j+3; read 6x6 patch with vertical reuse
    int u = tid >> 4, j = tid & 15;
    float acc[4][4];
#pragma unroll
    for (int m = 0; m < 4; ++m)
#pragma unroll
        for (int i = 0; i < 4; ++i) acc[m][i] = bv;

#define CONTRIB(m, t)                                                          \
    {                                                                          \
        float w0 = w[(t)*3 + 0], w1v = w[(t)*3 + 1], w2v = w[(t)*3 + 2];       \
        acc[m][0] += w0 * a0 + w1v * a1 + w2v * a2;                            \
        acc[m][1] += w0 * a1 + w1v * a2 + w2v * a3;                            \
        acc[m][2] += w0 * a2 + w1v * a3 + w2v * a4;                            \
        acc[m][3] += w0 * a3 + w1v * a4 + w2v * a5;                            \
    }
#define READROW(d)                                                             \
    float a0, a1, a2, a3, a4, a5;                                              \
    {                                                                          \
        int R = 4 * u + (d);                                                   \
        const float* r = &lds[R * LW + skew_of(R) + 3 + 4 * j];                \
        a0 = r[0]; a1 = r[1]; a2 = r[2]; a3 = r[3]; a4 = r[4]; a5 = r[5];      \
    }

    { READROW(0) CONTRIB(0, 0) }
    { READROW(1) CONTRIB(0, 1) CONTRIB(1, 0) }
    { READROW(2) CONTRIB(0, 2) CONTRIB(1, 1) CONTRIB(2, 0) }
    { READROW(3) CONTRIB(1, 2) CONTRIB(2, 1) CONTRIB(3, 0) }
    { READROW(4) CONTRIB(2, 2) CONTRIB(3, 1) }
    { READROW(5) CONTRIB(3, 2) }
#undef READROW
#undef CONTRIB

    // 7) store: 4 float4 rows, non-temporal (streaming output; keep x resident in L3)
    f4* op4 = (f4*)(out + (size_t)plane * HW);
#pragma unroll
    for (int m = 0; m < 4; ++m) {
        f4 o;
        o.x = acc[m][0]; o.y = acc[m][1]; o.z = acc[m][2]; o.w = acc[m][3];
        __builtin_nontemporal_store(o, &op4[(4 * u + m) * 16 + j]);
    }
}

extern "C" void kernel_launch(void* const* d_in, const int* in_sizes, int n_in,
                              void* d_out, int out_size, void* d_ws, size_t ws_size,
                              hipStream_t stream) {
    const float* x     = (const float*)d_in[0];
    const float* w1    = (const float*)d_in[1];
    const float* gamma = (const float*)d_in[2];
    const float* beta  = (const float*)d_in[3];
    const float* mean  = (const float*)d_in[4];
    const float* var   = (const float*)d_in[5];
    const float* w2    = (const float*)d_in[6];
    const float* b2    = (const float*)d_in[7];
    const float* bias  = (const float*)d_in[8];
    float* out = (float*)d_out;

    float* pooled = (float*)d_ws;            // 8192 floats
    float* sigg = pooled + 8192;             // 32*64 floats

    pool_kernel<<<8192, 256, 0, stream>>>(x, pooled);
    sig_kernel<<<32, 64, 0, stream>>>(pooled, w1, gamma, beta, mean, var, sigg);
    conv_kernel<<<8192, 256, 0, stream>>>(x, sigg, w2, b2, bias, out);
}